// Round 5
// baseline (496.222 us; speedup 1.0000x reference)
//
#include <hip/hip_runtime.h>
#include <math.h>

// B=512, C=256, H=W=14 -> L=196 (pad 208 rows / 224 K), D=512

typedef float f32x4 __attribute__((ext_vector_type(4)));
typedef short s16x8 __attribute__((ext_vector_type(8)));

__device__ __forceinline__ float wsum(float v) {
#pragma unroll
  for (int o = 32; o > 0; o >>= 1) v += __shfl_xor(v, o, 64);
  return v;
}

__device__ __forceinline__ unsigned short f2bf(float f) {
  unsigned int u = __float_as_uint(f);
  u += 0x7FFFu + ((u >> 16) & 1u);  // RNE
  return (unsigned short)(u >> 16);
}

__device__ __forceinline__ s16x8 pack8(f32x4 lo, f32x4 hi) {
  s16x8 r;
  r[0] = (short)f2bf(lo[0]);
  r[1] = (short)f2bf(lo[1]);
  r[2] = (short)f2bf(lo[2]);
  r[3] = (short)f2bf(lo[3]);
  r[4] = (short)f2bf(hi[0]);
  r[5] = (short)f2bf(hi[1]);
  r[6] = (short)f2bf(hi[2]);
  r[7] = (short)f2bf(hi[3]);
  return r;
}

// ---------------- Kernel: similarity weights -------------------------------
__global__ __launch_bounds__(256) void k_simw(const float* __restrict__ img,
                                              const float* __restrict__ txt,
                                              const float* __restrict__ Wsim,
                                              const float* __restrict__ bsim,
                                              float* __restrict__ simw) {
  const int b = blockIdx.x, tid = threadIdx.x, lane = tid & 63, wv = tid >> 6;
  __shared__ float s_img[512];
  __shared__ float s_part[3][4];

  float i0 = img[b * 512 + tid], i1 = img[b * 512 + 256 + tid];
  float t0 = txt[b * 512 + tid], t1 = txt[b * 512 + 256 + tid];
  float ssi = wsum(i0 * i0 + i1 * i1);
  float sst = wsum(t0 * t0 + t1 * t1);
  float dd = wsum(i0 * t0 + i1 * t1);
  if (lane == 0) { s_part[0][wv] = ssi; s_part[1][wv] = sst; s_part[2][wv] = dd; }
  __syncthreads();
  float ni = fmaxf(sqrtf(s_part[0][0] + s_part[0][1] + s_part[0][2] + s_part[0][3]), 1e-12f);
  float nt = fmaxf(sqrtf(s_part[1][0] + s_part[1][1] + s_part[1][2] + s_part[1][3]), 1e-12f);
  float dot = s_part[2][0] + s_part[2][1] + s_part[2][2] + s_part[2][3];
  float cross = dot / (ni * nt);
  float rni = 1.0f / ni;
  s_img[tid] = i0 * rni;
  s_img[tid + 256] = i1 * rni;
  __syncthreads();

  for (int l = wv; l < 196; l += 4) {
    const float* wr = Wsim + (size_t)l * 512;
    float p = 0.f;
#pragma unroll
    for (int k = 0; k < 8; ++k) p = fmaf(s_img[lane + 64 * k], wr[lane + 64 * k], p);
    p = wsum(p);
    if (lane == 0) {
      float z = p + bsim[l];
      float sg = 1.0f / (1.0f + __expf(-z));
      simw[b * 196 + l] = cross * sg * 0.1f;
    }
  }
}

// ---------------- Kernel: prep v2 — RAW transposed bf16 + inv norms --------
// Single pass over sam: stage 64-row tile in LDS, accumulate column ssq from
// LDS, transpose-pack RAW bf16 into samnT. inv norms written separately and
// applied as f32 scale on scores (bilinear). Rows l=196..207 zero.
// Also zeroes attnT pad columns 208..223.
__global__ __launch_bounds__(256) void k_prep2(const float* __restrict__ sam,
                                               unsigned short* __restrict__ samnT,
                                               unsigned short* __restrict__ attnT,
                                               float* __restrict__ invn) {
  const int b = blockIdx.x, tid = threadIdx.x, lane = tid & 63, wv = tid >> 6;
  const float* __restrict__ S = sam + (size_t)b * 50176;
  unsigned short* __restrict__ NT = samnT + (size_t)b * (208 * 256);
  unsigned short* __restrict__ ATz = attnT + (size_t)b * (208 * 224);
  __shared__ float T[64 * 197];
  __shared__ float s_ss[196];

  // zero attnT[:, 208..223]
  for (int i = tid; i < 208 * 8; i += 256) {
    int m = i >> 3, k = i & 7;
    ((unsigned int*)(ATz + m * 224 + 208))[k] = 0;
  }
  // zero NT pad rows l=196..207
  for (int i = tid; i < 1536; i += 256) ((unsigned int*)(NT + 196 * 256))[i] = 0;
  if (tid < 196) s_ss[tid] = 0.f;

  for (int c0 = 0; c0 < 256; c0 += 64) {
    __syncthreads();
    for (int cr = wv; cr < 64; cr += 4) {
      const float* Sr = S + (c0 + cr) * 196;
      float* Tr = T + cr * 197;
      Tr[lane] = Sr[lane];
      Tr[lane + 64] = Sr[lane + 64];
      Tr[lane + 128] = Sr[lane + 128];
      if (lane < 4) Tr[lane + 192] = Sr[lane + 192];
    }
    __syncthreads();
    // column sum-of-squares partial from LDS (conflict-free: consecutive l)
    if (tid < 196) {
      float p = 0.f;
      for (int cr = 0; cr < 64; ++cr) {
        float v = T[cr * 197 + tid];
        p = fmaf(v, v, p);
      }
      s_ss[tid] += p;
    }
    // transpose-pack RAW bf16
    const int lrow = tid >> 3, cch = tid & 7;
    for (int l0 = 0; l0 < 196; l0 += 32) {
      int l = l0 + lrow;
      if (l < 196) {
        const float* Tc = T + (cch * 8) * 197 + l;
        unsigned short r[8];
#pragma unroll
        for (int k = 0; k < 8; ++k) r[k] = f2bf(Tc[k * 197]);
        uint4 o;
        o.x = r[0] | ((unsigned int)r[1] << 16);
        o.y = r[2] | ((unsigned int)r[3] << 16);
        o.z = r[4] | ((unsigned int)r[5] << 16);
        o.w = r[6] | ((unsigned int)r[7] << 16);
        *(uint4*)(NT + l * 256 + c0 + cch * 8) = o;
      }
    }
  }
  if (tid < 196) invn[b * 196 + tid] = 1.0f / fmaxf(sqrtf(s_ss[tid]), 1e-12f);
}

// ---------------- scores softmax epilogue ----------------------------------
__device__ __forceinline__ void proc_strip(int s, f32x4* sc, unsigned short* AT,
                                           int quad, int l15) {
  const bool mval12 = (192 + l15) < 196;  // j==12 column validity
  float mx[4], rs[4];
#pragma unroll
  for (int r = 0; r < 4; ++r) {
    float m = -3e38f;
#pragma unroll
    for (int j = 0; j < 13; ++j) {
      float v = sc[j][r];
      if (j == 12 && !mval12) v = -3e38f;
      m = fmaxf(m, v);
    }
#pragma unroll
    for (int o = 1; o < 16; o <<= 1) m = fmaxf(m, __shfl_xor(m, o, 64));
    float s_ = 0.f;
#pragma unroll
    for (int j = 0; j < 13; ++j) {
      float e = __expf(sc[j][r] - m);
      if (j == 12 && !mval12) e = 0.f;
      s_ += e;
    }
#pragma unroll
    for (int o = 1; o < 16; o <<= 1) s_ += __shfl_xor(s_, o, 64);
    mx[r] = m;
    rs[r] = 1.0f / s_;
  }
  const int lb = s * 16 + quad * 4;
#pragma unroll
  for (int j = 0; j < 13; ++j) {
    unsigned short u[4];
#pragma unroll
    for (int r = 0; r < 4; ++r) {
      float a = __expf(sc[j][r] - mx[r]) * rs[r];
      if (lb + r >= 196) a = 0.f;  // K-padding rows of attn must be zero
      u[r] = f2bf(a);
    }
    uint2 o2;
    o2.x = u[0] | ((unsigned int)u[1] << 16);
    o2.y = u[2] | ((unsigned int)u[3] << 16);
    *(uint2*)(AT + (j * 16 + l15) * 224 + lb) = o2;
  }
}

// ---------------- Kernel: scores GEMM + softmax -> attnT (v2b) -------------
// One wave per output strip s. Raw-bf16 MFMA then f32 inv_l*inv_m scaling.
__global__ __launch_bounds__(64) void k_scores2(const unsigned short* __restrict__ samnT,
                                                const float* __restrict__ invn,
                                                unsigned short* __restrict__ attnT) {
  int id = blockIdx.x;
  int b, s;
  if (gridDim.x == 512 * 13) {
    int x = id & 7, j = id >> 3;  // 832 blocks per XCD = 64 batches * 13
    int bb = j / 13;
    b = x * 64 + bb;
    s = j - bb * 13;
  } else {
    int bb = id / 13;
    b = bb;
    s = id - bb * 13;
  }
  const int lane = threadIdx.x, quad = lane >> 4, l15 = lane & 15;
  const unsigned short* __restrict__ NT = samnT + (size_t)b * (208 * 256);
  unsigned short* __restrict__ AT = attnT + (size_t)b * (208 * 224);

  s16x8 A[8];
  const unsigned short* Ar = NT + (s * 16 + l15) * 256 + quad * 8;
#pragma unroll
  for (int ct = 0; ct < 8; ++ct) A[ct] = *(const s16x8*)(Ar + ct * 32);

  f32x4 sc[13];
  const f32x4 z = {0.f, 0.f, 0.f, 0.f};
#pragma unroll
  for (int j = 0; j < 13; ++j) sc[j] = z;

#pragma unroll
  for (int j = 0; j < 13; ++j) {
    const unsigned short* Br = NT + (j * 16 + l15) * 256 + quad * 8;
#pragma unroll
    for (int ct = 0; ct < 8; ++ct) {
      s16x8 Bf = *(const s16x8*)(Br + ct * 32);
      sc[j] = __builtin_amdgcn_mfma_f32_16x16x32_bf16(A[ct], Bf, sc[j], 0, 0, 0);
    }
  }

  // scale by inv_norm[row] * inv_norm[col]
  float ivA[4];
#pragma unroll
  for (int r = 0; r < 4; ++r) {
    int row = s * 16 + quad * 4 + r;
    ivA[r] = (row < 196) ? invn[b * 196 + row] : 0.f;
  }
#pragma unroll
  for (int j = 0; j < 13; ++j) {
    int m = j * 16 + l15;
    float ivB = (m < 196) ? invn[b * 196 + m] : 0.f;
#pragma unroll
    for (int r = 0; r < 4; ++r) sc[j][r] *= ivA[r] * ivB;
  }

  proc_strip(s, sc, AT, quad, l15);
}

// ---------------- Kernel: weighted GEMM + guide epilogue (v2+stats) --------
// Grid (B, 4): block (b, q) computes channels c = q*64 .. q*64+63.
// Also accumulates per-block channel-stat partials (sum x, sum x^2 over its
// 64 channels, per m) into stats[b][q][2][196] for k_norm2 (non-atomic).
// [PROVEN round 2: 103 µs, passed.]
__global__ __launch_bounds__(256, 4) void k_weighted2(const float* __restrict__ sam,
                                                      const unsigned short* __restrict__ attnT,
                                                      const float* __restrict__ simw,
                                                      float* __restrict__ out,
                                                      float* __restrict__ stats) {
  const int b = blockIdx.x, q = blockIdx.y;
  const int tid = threadIdx.x, lane = tid & 63, wv = tid >> 6;
  const int quad = lane >> 4, l15 = lane & 15;
  const float* __restrict__ S = sam + (size_t)b * 50176;
  const unsigned short* __restrict__ AT = attnT + (size_t)b * (208 * 224);
  float* __restrict__ O = out + (size_t)b * 50176;
  const int cbase = q * 64 + wv * 16;

  __shared__ float tile[4][8 * 196];  // 25088 B, per-wave epilogue staging

  f32x4 acc[13];
  const f32x4 z4 = {0.f, 0.f, 0.f, 0.f};
#pragma unroll
  for (int mb = 0; mb < 13; ++mb) acc[mb] = z4;

  // A row for this lane: c = cbase + l15; k slice: kt*32 + quad*8 .. +7
  const float* __restrict__ Sa = S + (size_t)(cbase + l15) * 196;
  const unsigned short* __restrict__ Bp = AT + l15 * 224 + quad * 8;

#pragma unroll
  for (int kt = 0; kt < 7; ++kt) {
    s16x8 A;
    if (kt < 6) {
      const float* p = Sa + kt * 32 + quad * 8;
      A = pack8(*(const f32x4*)p, *(const f32x4*)(p + 4));
    } else {
      f32x4 lo = z4;
      if (quad == 0) lo = *(const f32x4*)(Sa + 192);
      A = pack8(lo, z4);
    }
    const unsigned short* Bk = Bp + kt * 32;
#pragma unroll
    for (int mb = 0; mb < 13; ++mb) {
      s16x8 Bf = *(const s16x8*)(Bk + mb * 16 * 224);
      acc[mb] = __builtin_amdgcn_mfma_f32_16x16x32_bf16(A, Bf, acc[mb], 0, 0, 0);
    }
  }

  // ---- epilogue: out[c][m] = (S[c][m] + acc) * simw[m] * 0.5 ----
  float wj0 = simw[b * 196 + lane] * 0.5f;
  float wj1 = simw[b * 196 + 64 + lane] * 0.5f;
  float wj2 = simw[b * 196 + 128 + lane] * 0.5f;
  float wj3 = 0.f;
  if (lane < 4) wj3 = simw[b * 196 + 192 + lane] * 0.5f;

  float st0 = 0.f, st1 = 0.f, st2 = 0.f, st3 = 0.f;
  float sq0 = 0.f, sq1 = 0.f, sq2 = 0.f, sq3 = 0.f;

  float* tl = &tile[wv][0];
  for (int half = 0; half < 2; ++half) {
    if ((quad >> 1) == half) {
      const int qq = quad & 1;
#pragma unroll
      for (int mb = 0; mb < 13; ++mb) {
        const int m = mb * 16 + l15;
        if (m < 196) {
#pragma unroll
          for (int r = 0; r < 4; ++r) tl[(qq * 4 + r) * 196 + m] = acc[mb][r];
        }
      }
    }
    __syncthreads();
    const int rowg0 = cbase + half * 8;
#pragma unroll
    for (int rr = 0; rr < 8; ++rr) {
      const float* trow = tl + rr * 196;
      const float* Sr = S + (size_t)(rowg0 + rr) * 196;
      float* Or = O + (size_t)(rowg0 + rr) * 196;
      float v0 = (Sr[lane] + trow[lane]) * wj0;
      float v1 = (Sr[lane + 64] + trow[lane + 64]) * wj1;
      float v2 = (Sr[lane + 128] + trow[lane + 128]) * wj2;
      Or[lane] = v0;
      Or[lane + 64] = v1;
      Or[lane + 128] = v2;
      st0 += v0; sq0 = fmaf(v0, v0, sq0);
      st1 += v1; sq1 = fmaf(v1, v1, sq1);
      st2 += v2; sq2 = fmaf(v2, v2, sq2);
      if (lane < 4) {
        float v3 = (Sr[lane + 192] + trow[lane + 192]) * wj3;
        Or[lane + 192] = v3;
        st3 += v3; sq3 = fmaf(v3, v3, sq3);
      }
    }
    __syncthreads();
  }

  // ---- channel-stat partials: per-wave regs -> LDS -> global (non-atomic)
  tl[lane] = st0; tl[lane + 64] = st1; tl[lane + 128] = st2;
  if (lane < 4) tl[lane + 192] = st3;
  tl[784 + lane] = sq0; tl[784 + lane + 64] = sq1; tl[784 + lane + 128] = sq2;
  if (lane < 4) tl[784 + lane + 192] = sq3;
  __syncthreads();
  if (tid < 196) {
    float s = tile[0][tid] + tile[1][tid] + tile[2][tid] + tile[3][tid];
    float qsum = tile[0][784 + tid] + tile[1][784 + tid] + tile[2][784 + tid] + tile[3][784 + tid];
    stats[((size_t)(b * 4 + q) * 2 + 0) * 196 + tid] = s;
    stats[((size_t)(b * 4 + q) * 2 + 1) * 196 + tid] = qsum;
  }
}

// ---------------- Kernel: hierarchical norm v2 -----------------------------
// [PROVEN round 2.]
__global__ __launch_bounds__(256) void k_norm2(float* __restrict__ x,
                                               const float* __restrict__ stats) {
  const int b = blockIdx.x, q = blockIdx.y, tid = threadIdx.x;
  float* __restrict__ X = x + (size_t)b * 50176 + (size_t)q * 128 * 196;
  __shared__ float s_mu[196], s_rs[196];
  __shared__ float s_rm[32], s_rc[32];
  __shared__ float T[32][197];

  if (tid < 196) {
    const float* st = stats + (size_t)b * 8 * 196;
    float s = st[tid] + st[2 * 196 + tid] + st[4 * 196 + tid] + st[6 * 196 + tid];
    float sq = st[196 + tid] + st[3 * 196 + tid] + st[5 * 196 + tid] + st[7 * 196 + tid];
    float mu = s * (1.0f / 256.0f);
    float var = sq * (1.0f / 256.0f) - mu * mu;
    s_mu[tid] = mu;
    s_rs[tid] = rsqrtf(fmaxf(var, 0.f) + 1e-5f);
  }
  __syncthreads();

  for (int rg = 0; rg < 4; ++rg) {
    float* Xg = X + rg * 32 * 196;
    for (int i = tid; i < 32 * 196; i += 256) T[i / 196][i % 196] = Xg[i];
    __syncthreads();
    const int r = tid >> 3, p = tid & 7;
    float ys = 0.f, yq = 0.f;
    for (int m = p; m < 196; m += 8) {
      float y = (T[r][m] - s_mu[m]) * s_rs[m];
      ys += y;
      yq = fmaf(y, y, yq);
    }
    ys += __shfl_xor(ys, 1, 64); yq += __shfl_xor(yq, 1, 64);
    ys += __shfl_xor(ys, 2, 64); yq += __shfl_xor(yq, 2, 64);
    ys += __shfl_xor(ys, 4, 64); yq += __shfl_xor(yq, 4, 64);
    if (p == 0) {
      float rm = ys * (1.0f / 196.0f);
      float var = (yq - 196.0f * rm * rm) * (1.0f / 195.0f);
      float sd = sqrtf(fmaxf(var, 0.f));
      s_rm[r] = rm;
      s_rc[r] = 1.0f / (sd + 1e-6f);
    }
    __syncthreads();
    for (int i = tid; i < 32 * 196; i += 256) {
      int rr = i / 196, m = i % 196;
      float y = (T[rr][m] - s_mu[m]) * s_rs[m];
      Xg[i] = (y - s_rm[rr]) * s_rc[rr];
    }
    __syncthreads();
  }
}

// ---------------- Fallback fp32 fused attention ----------------------------
__global__ __launch_bounds__(256) void k_attn(const float* __restrict__ sam,
                                              const float* __restrict__ simw,
                                              float* __restrict__ out) {
  const int b = blockIdx.x;
  const int tid = threadIdx.x, lane = tid & 63, wv = tid >> 6;
  const float* __restrict__ S = sam + (size_t)b * (256 * 196);
  float* __restrict__ O = out + (size_t)b * (256 * 196);
  const float* __restrict__ SW = simw + b * 196;

  __shared__ float s_inv[196];
  __shared__ float s_max[196];
  __shared__ float s_rsum[196];
  __shared__ float bufS[28 * 197];
  __shared__ float bufT[256 * 29];

  for (int l = tid; l < 196; l += 256) {
    float ss = 0.f;
    for (int c = 0; c < 256; ++c) {
      float v = S[c * 196 + l];
      ss = fmaf(v, v, ss);
    }
    s_inv[l] = 1.0f / fmaxf(sqrtf(ss), 1e-12f);
  }

  for (int r0 = 0; r0 < 196; r0 += 28) {
    float acc[7][4];
#pragma unroll
    for (int i = 0; i < 7; ++i)
#pragma unroll
      for (int j = 0; j < 4; ++j) acc[i][j] = 0.f;
    const int lr = r0 + wv * 7;
    for (int ct = 0; ct < 8; ++ct) {
      __syncthreads();
      for (int i = tid; i < 32 * 196; i += 256)
        bufT[(i / 196) * 197 + (i % 196)] = S[ct * 32 * 196 + i];
      __syncthreads();
#pragma unroll 2
      for (int c = 0; c < 32; ++c) {
        const float* row = bufT + c * 197;
        float a[7];
#pragma unroll
        for (int i = 0; i < 7; ++i) a[i] = row[lr + i];
        float b0 = row[lane], b1 = row[lane + 64], b2 = row[lane + 128];
        float b3 = row[lane + 192];
#pragma unroll
        for (int i = 0; i < 7; ++i) {
          acc[i][0] = fmaf(a[i], b0, acc[i][0]);
          acc[i][1] = fmaf(a[i], b1, acc[i][1]);
          acc[i][2] = fmaf(a[i], b2, acc[i][2]);
          acc[i][3] = fmaf(a[i], b3, acc[i][3]);
        }
      }
    }
#pragma unroll
    for (int j = 0; j < 4; ++j) {
      int m = lane + 64 * j;
      if (m < 196) {
        float im = s_inv[m] * 0.0625f;
#pragma unroll
        for (int i = 0; i < 7; ++i)
          bufS[(wv * 7 + i) * 197 + m] = acc[i][j] * s_inv[lr + i] * im;
      }
    }
    __syncthreads();
#pragma unroll
    for (int i = 0; i < 7; ++i) {
      const int rl = wv * 7 + i;
      const float* sr = bufS + rl * 197;
      float v0 = sr[lane], v1 = sr[lane + 64], v2 = sr[lane + 128];
      bool g = (lane + 192) < 196;
      float v3 = g ? sr[lane + 192] : -1e30f;
      float mxv = fmaxf(fmaxf(v0, v1), fmaxf(v2, v3));
#pragma unroll
      for (int o = 32; o > 0; o >>= 1) mxv = fmaxf(mxv, __shfl_xor(mxv, o, 64));
      float sm = __expf(v0 - mxv) + __expf(v1 - mxv) + __expf(v2 - mxv) +
                 (g ? __expf(v3 - mxv) : 0.f);
      sm = wsum(sm);
      if (lane == 0) { s_max[r0 + rl] = mxv; s_rsum[r0 + rl] = 1.0f / sm; }
    }
  }
  __syncthreads();

  const int cg = tid >> 2, tq = tid & 3;
  for (int m0 = 0; m0 < 196; m0 += 28) {
    float acc[7][4];
#pragma unroll
    for (int i = 0; i < 7; ++i)
#pragma unroll
      for (int j = 0; j < 4; ++j) acc[i][j] = 0.f;
    const int mg = m0 + wv * 7;
    for (int ct = 0; ct < 8; ++ct) {
      __syncthreads();
      for (int i = tid; i < 32 * 196; i += 256)
        bufT[(i / 196) * 197 + (i % 196)] = S[ct * 32 * 196 + i];
      __syncthreads();
#pragma unroll 2
      for (int c = 0; c < 32; ++c) {
        const float* row = bufT + c * 197;
        float a[7];
#pragma unroll
        for (int i = 0; i < 7; ++i) a[i] = row[mg + i];
        float b0 = row[lane], b1 = row[lane + 64], b2 = row[lane + 128];
        float b3 = row[lane + 192];
#pragma unroll
        for (int i = 0; i < 7; ++i) {
          acc[i][0] = fmaf(a[i], b0, acc[i][0]);
          acc[i][1] = fmaf(a[i], b1, acc[i][1]);
          acc[i][2] = fmaf(a[i], b2, acc[i][2]);
          acc[i][3] = fmaf(a[i], b3, acc[i][3]);
        }
      }
    }
    __syncthreads();
#pragma unroll
    for (int j = 0; j < 4; ++j) {
      int l = lane + 64 * j;
      if (l < 196) {
        float il = s_inv[l] * 0.0625f;
        float mxl = s_max[l], rsl = s_rsum[l];
#pragma unroll
        for (int i = 0; i < 7; ++i) {
          float sc = acc[i][j] * s_inv[mg + i] * il;
          bufS[(wv * 7 + i) * 197 + l] = __expf(sc - mxl) * rsl;
        }
      }
    }
    __syncthreads();
    float w[4][7];
#pragma unroll
    for (int ii = 0; ii < 4; ++ii)
#pragma unroll
      for (int i = 0; i < 7; ++i) w[ii][i] = 0.f;
    for (int lt = 0; lt < 7; ++lt) {
      __syncthreads();
      for (int i = tid; i < 256 * 28; i += 256) {
        int c = i / 28, j = i - c * 28;
        bufT[c * 29 + j] = S[c * 196 + lt * 28 + j];
      }
      __syncthreads();
#pragma unroll 4
      for (int j = 0; j < 28; ++j) {
        float a0 = bufT[(cg * 4 + 0) * 29 + j];
        float a1 = bufT[(cg * 4 + 1) * 29 + j];
        float a2 = bufT[(cg * 4 + 2) * 29 + j];
        float a3 = bufT[(cg * 4 + 3) * 29 + j];
#pragma unroll
        for (int i = 0; i < 7; ++i) {
          float bv = bufS[(tq * 7 + i) * 197 + lt * 28 + j];
          w[0][i] = fmaf(a0, bv, w[0][i]);
          w[1][i] = fmaf(a1, bv, w[1][i]);
          w[2][i] = fmaf(a2, bv, w[2][i]);
          w[3][i] = fmaf(a3, bv, w[3][i]);
        }
      }
    }
#pragma unroll
    for (int i = 0; i < 7; ++i) {
      const int m = m0 + tq * 7 + i;
      float sw = SW[m] * 0.5f;
#pragma unroll
      for (int ii = 0; ii < 4; ++ii) {
        const int c = cg * 4 + ii;
        O[c * 196 + m] = (S[c * 196 + m] + w[ii][i]) * sw;
      }
    }
  }
}

// ---------------- Kernel: hierarchical norm (fallback, in-place) -----------
__global__ __launch_bounds__(256) void k_norm(float* __restrict__ x) {
  const int b = blockIdx.x, tid = threadIdx.x;
  float* __restrict__ X = x + (size_t)b * (256 * 196);
  __shared__ float s_mu[196], s_rs[196];
  __shared__ float s_rm[256], s_rc[256];
  __shared__ float tile[256 * 29];

  if (tid < 196) {
    float s = 0.f, q = 0.f;
    for (int c = 0; c < 256; ++c) {
      float v = X[c * 196 + tid];
      s += v;
      q = fmaf(v, v, q);
    }
    float mu = s * (1.0f / 256.0f);
    float var = q * (1.0f / 256.0f) - mu * mu;
    s_mu[tid] = mu;
    s_rs[tid] = rsqrtf(fmaxf(var, 0.f) + 1e-5f);
  }
  __syncthreads();

  float rs = 0.f, rq = 0.f;
  for (int m0 = 0; m0 < 196; m0 += 28) {
    __syncthreads();
    for (int i = tid; i < 256 * 28; i += 256) {
      int c = i / 28, j = i - c * 28;
      tile[c * 29 + j] = X[c * 196 + m0 + j];
    }
    __syncthreads();
#pragma unroll
    for (int j = 0; j < 28; ++j) {
      float y = (tile[tid * 29 + j] - s_mu[m0 + j]) * s_rs[m0 + j];
      rs += y;
      rq = fmaf(y, y, rq);
    }
  }
  float rm = rs * (1.0f / 196.0f);
  float var = (rq - 196.0f * rm * rm) * (1.0f / 195.0f);
  float sd = sqrtf(fmaxf(var, 0.f));
  s_rm[tid] = rm;
  s_rc[tid] = 1.0f / (sd + 1e-6f);
  __syncthreads();

  for (int i = tid; i < 256 * 196; i += 256) {
    int c = i / 196, m = i - c * 196;
    float y = (X[i] - s_mu[m]) * s_rs[m];
    X[i] = (y - s_rm[c]) * s_rc[c];
  }
}

extern "C" void kernel_launch(void* const* d_in, const int* in_sizes, int n_in,
                              void* d_out, int out_size, void* d_ws, size_t ws_size,
                              hipStream_t stream) {
  const float* img = (const float*)d_in[0];
  const float* txt = (const float*)d_in[1];
  const float* sam = (const float*)d_in[2];
  const float* Wsim = (const float*)d_in[3];
  const float* bsim = (const float*)d_in[4];
  float* out = (float*)d_out;

  const int B = in_sizes[0] / 512;  // 512

  const size_t simw_bytes = (((size_t)B * 196 * 4) + 511) & ~(size_t)511;
  const size_t samnT_bytes = (size_t)B * 208 * 256 * 2;
  const size_t attnT_bytes = (size_t)B * 208 * 224 * 2;
  const size_t stats_bytes = (size_t)B * 4 * 2 * 196 * 4;
  const size_t invn_bytes = (((size_t)B * 196 * 4) + 511) & ~(size_t)511;
  const size_t need = simw_bytes + samnT_bytes + attnT_bytes + stats_bytes + invn_bytes;

  float* simw = (float*)d_ws;

  k_simw<<<B, 256, 0, stream>>>(img, txt, Wsim, bsim, simw);

  if (ws_size >= need) {
    unsigned short* samnT = (unsigned short*)((char*)d_ws + simw_bytes);
    unsigned short* attnT = (unsigned short*)((char*)d_ws + simw_bytes + samnT_bytes);
    float* stats = (float*)((char*)d_ws + simw_bytes + samnT_bytes + attnT_bytes);
    float* invn = (float*)((char*)d_ws + simw_bytes + samnT_bytes + attnT_bytes + stats_bytes);
    k_prep2<<<B, 256, 0, stream>>>(sam, samnT, attnT, invn);
    k_scores2<<<B * 13, 64, 0, stream>>>(samnT, invn, attnT);
    k_weighted2<<<dim3(B, 4), 256, 0, stream>>>(sam, attnT, simw, out, stats);
    k_norm2<<<dim3(B, 2), 256, 0, stream>>>(out, stats);
  } else {
    k_attn<<<B, 256, 0, stream>>>(sam, simw, out);
    k_norm<<<B, 256, 0, stream>>>(out);
  }
}

// Round 6
// 470.664 us; speedup vs baseline: 1.0543x; 1.0543x over previous
//
#include <hip/hip_runtime.h>
#include <math.h>

// B=512, C=256, H=W=14 -> L=196 (pad 208 rows / 224 K), D=512

typedef float f32x4 __attribute__((ext_vector_type(4)));
typedef short s16x8 __attribute__((ext_vector_type(8)));

__device__ __forceinline__ float wsum(float v) {
#pragma unroll
  for (int o = 32; o > 0; o >>= 1) v += __shfl_xor(v, o, 64);
  return v;
}

__device__ __forceinline__ unsigned short f2bf(float f) {
  unsigned int u = __float_as_uint(f);
  u += 0x7FFFu + ((u >> 16) & 1u);  // RNE
  return (unsigned short)(u >> 16);
}

__device__ __forceinline__ s16x8 pack8(f32x4 lo, f32x4 hi) {
  s16x8 r;
  r[0] = (short)f2bf(lo[0]);
  r[1] = (short)f2bf(lo[1]);
  r[2] = (short)f2bf(lo[2]);
  r[3] = (short)f2bf(lo[3]);
  r[4] = (short)f2bf(hi[0]);
  r[5] = (short)f2bf(hi[1]);
  r[6] = (short)f2bf(hi[2]);
  r[7] = (short)f2bf(hi[3]);
  return r;
}

// ---------------- Kernel: similarity weights -------------------------------
__global__ __launch_bounds__(256) void k_simw(const float* __restrict__ img,
                                              const float* __restrict__ txt,
                                              const float* __restrict__ Wsim,
                                              const float* __restrict__ bsim,
                                              float* __restrict__ simw) {
  const int b = blockIdx.x, tid = threadIdx.x, lane = tid & 63, wv = tid >> 6;
  __shared__ float s_img[512];
  __shared__ float s_part[3][4];

  float i0 = img[b * 512 + tid], i1 = img[b * 512 + 256 + tid];
  float t0 = txt[b * 512 + tid], t1 = txt[b * 512 + 256 + tid];
  float ssi = wsum(i0 * i0 + i1 * i1);
  float sst = wsum(t0 * t0 + t1 * t1);
  float dd = wsum(i0 * t0 + i1 * t1);
  if (lane == 0) { s_part[0][wv] = ssi; s_part[1][wv] = sst; s_part[2][wv] = dd; }
  __syncthreads();
  float ni = fmaxf(sqrtf(s_part[0][0] + s_part[0][1] + s_part[0][2] + s_part[0][3]), 1e-12f);
  float nt = fmaxf(sqrtf(s_part[1][0] + s_part[1][1] + s_part[1][2] + s_part[1][3]), 1e-12f);
  float dot = s_part[2][0] + s_part[2][1] + s_part[2][2] + s_part[2][3];
  float cross = dot / (ni * nt);
  float rni = 1.0f / ni;
  s_img[tid] = i0 * rni;
  s_img[tid + 256] = i1 * rni;
  __syncthreads();

  for (int l = wv; l < 196; l += 4) {
    const float* wr = Wsim + (size_t)l * 512;
    float p = 0.f;
#pragma unroll
    for (int k = 0; k < 8; ++k) p = fmaf(s_img[lane + 64 * k], wr[lane + 64 * k], p);
    p = wsum(p);
    if (lane == 0) {
      float z = p + bsim[l];
      float sg = 1.0f / (1.0f + __expf(-z));
      simw[b * 196 + l] = cross * sg * 0.1f;
    }
  }
}

// ---------------- Kernel: prep v2 — RAW transposed bf16 + inv norms --------
// Single pass over sam: stage 64-row tile in LDS, accumulate column ssq from
// LDS, transpose-pack RAW bf16 into samnT. inv norms written separately and
// applied as f32 scale on scores (bilinear). Rows l=196..207 zero.
// Also zeroes attnT pad columns 208..223. [PROVEN round 5.]
__global__ __launch_bounds__(256) void k_prep2(const float* __restrict__ sam,
                                               unsigned short* __restrict__ samnT,
                                               unsigned short* __restrict__ attnT,
                                               float* __restrict__ invn) {
  const int b = blockIdx.x, tid = threadIdx.x, lane = tid & 63, wv = tid >> 6;
  const float* __restrict__ S = sam + (size_t)b * 50176;
  unsigned short* __restrict__ NT = samnT + (size_t)b * (208 * 256);
  unsigned short* __restrict__ ATz = attnT + (size_t)b * (208 * 224);
  __shared__ float T[64 * 197];
  __shared__ float s_ss[196];

  // zero attnT[:, 208..223]
  for (int i = tid; i < 208 * 8; i += 256) {
    int m = i >> 3, k = i & 7;
    ((unsigned int*)(ATz + m * 224 + 208))[k] = 0;
  }
  // zero NT pad rows l=196..207
  for (int i = tid; i < 1536; i += 256) ((unsigned int*)(NT + 196 * 256))[i] = 0;
  if (tid < 196) s_ss[tid] = 0.f;

  for (int c0 = 0; c0 < 256; c0 += 64) {
    __syncthreads();
    for (int cr = wv; cr < 64; cr += 4) {
      const float* Sr = S + (c0 + cr) * 196;
      float* Tr = T + cr * 197;
      Tr[lane] = Sr[lane];
      Tr[lane + 64] = Sr[lane + 64];
      Tr[lane + 128] = Sr[lane + 128];
      if (lane < 4) Tr[lane + 192] = Sr[lane + 192];
    }
    __syncthreads();
    // column sum-of-squares partial from LDS (conflict-free: consecutive l)
    if (tid < 196) {
      float p = 0.f;
      for (int cr = 0; cr < 64; ++cr) {
        float v = T[cr * 197 + tid];
        p = fmaf(v, v, p);
      }
      s_ss[tid] += p;
    }
    // transpose-pack RAW bf16
    const int lrow = tid >> 3, cch = tid & 7;
    for (int l0 = 0; l0 < 196; l0 += 32) {
      int l = l0 + lrow;
      if (l < 196) {
        const float* Tc = T + (cch * 8) * 197 + l;
        unsigned short r[8];
#pragma unroll
        for (int k = 0; k < 8; ++k) r[k] = f2bf(Tc[k * 197]);
        uint4 o;
        o.x = r[0] | ((unsigned int)r[1] << 16);
        o.y = r[2] | ((unsigned int)r[3] << 16);
        o.z = r[4] | ((unsigned int)r[5] << 16);
        o.w = r[6] | ((unsigned int)r[7] << 16);
        *(uint4*)(NT + l * 256 + c0 + cch * 8) = o;
      }
    }
  }
  if (tid < 196) invn[b * 196 + tid] = 1.0f / fmaxf(sqrtf(s_ss[tid]), 1e-12f);
}

// ---------------- scores softmax epilogue ----------------------------------
__device__ __forceinline__ void proc_strip(int s, f32x4* sc, unsigned short* AT,
                                           int quad, int l15) {
  const bool mval12 = (192 + l15) < 196;  // j==12 column validity
  float mx[4], rs[4];
#pragma unroll
  for (int r = 0; r < 4; ++r) {
    float m = -3e38f;
#pragma unroll
    for (int j = 0; j < 13; ++j) {
      float v = sc[j][r];
      if (j == 12 && !mval12) v = -3e38f;
      m = fmaxf(m, v);
    }
#pragma unroll
    for (int o = 1; o < 16; o <<= 1) m = fmaxf(m, __shfl_xor(m, o, 64));
    float s_ = 0.f;
#pragma unroll
    for (int j = 0; j < 13; ++j) {
      float e = __expf(sc[j][r] - m);
      if (j == 12 && !mval12) e = 0.f;
      s_ += e;
    }
#pragma unroll
    for (int o = 1; o < 16; o <<= 1) s_ += __shfl_xor(s_, o, 64);
    mx[r] = m;
    rs[r] = 1.0f / s_;
  }
  const int lb = s * 16 + quad * 4;
#pragma unroll
  for (int j = 0; j < 13; ++j) {
    unsigned short u[4];
#pragma unroll
    for (int r = 0; r < 4; ++r) {
      float a = __expf(sc[j][r] - mx[r]) * rs[r];
      if (lb + r >= 196) a = 0.f;  // K-padding rows of attn must be zero
      u[r] = f2bf(a);
    }
    uint2 o2;
    o2.x = u[0] | ((unsigned int)u[1] << 16);
    o2.y = u[2] | ((unsigned int)u[3] << 16);
    *(uint2*)(AT + (j * 16 + l15) * 224 + lb) = o2;
  }
}

// ---------------- Kernel: scores GEMM + softmax -> attnT (v3) --------------
// One wave per PAIR of output strips (s0=2p, s1=min(2p+1,12)). Each B
// fragment is loaded ONCE from L2-hot samnT and feeds both strips' MFMA
// chains: halves total B traffic and doubles MFMA per load-latency vs v2.
// K-accumulation order (ct 0..7) bitwise identical to v2. XCD grouping:
// id%8 -> xcd, 64 batches per xcd.
__global__ __launch_bounds__(64) void k_scores3(const unsigned short* __restrict__ samnT,
                                                const float* __restrict__ invn,
                                                unsigned short* __restrict__ attnT) {
  int id = blockIdx.x;
  int b, p;
  if (gridDim.x == 512 * 7) {
    int x = id & 7, j = id >> 3;  // 448 blocks per XCD = 64 batches * 7
    int bb = j / 7;
    b = x * 64 + bb;
    p = j - bb * 7;
  } else {
    int bb = id / 7;
    b = bb;
    p = id - bb * 7;
  }
  const int s0 = 2 * p, s1 = (2 * p + 1 < 13) ? (2 * p + 1) : 12;
  const int lane = threadIdx.x, quad = lane >> 4, l15 = lane & 15;
  const unsigned short* __restrict__ NT = samnT + (size_t)b * (208 * 256);
  unsigned short* __restrict__ AT = attnT + (size_t)b * (208 * 224);

  s16x8 A0[8], A1[8];
  const unsigned short* Ar0 = NT + (s0 * 16 + l15) * 256 + quad * 8;
  const unsigned short* Ar1 = NT + (s1 * 16 + l15) * 256 + quad * 8;
#pragma unroll
  for (int ct = 0; ct < 8; ++ct) {
    A0[ct] = *(const s16x8*)(Ar0 + ct * 32);
    A1[ct] = *(const s16x8*)(Ar1 + ct * 32);
  }

  f32x4 sc0[13], sc1[13];
  const f32x4 z = {0.f, 0.f, 0.f, 0.f};
#pragma unroll
  for (int j = 0; j < 13; ++j) { sc0[j] = z; sc1[j] = z; }

#pragma unroll
  for (int j = 0; j < 13; ++j) {
    const unsigned short* Br = NT + (j * 16 + l15) * 256 + quad * 8;
#pragma unroll
    for (int ct = 0; ct < 8; ++ct) {
      s16x8 Bf = *(const s16x8*)(Br + ct * 32);
      sc0[j] = __builtin_amdgcn_mfma_f32_16x16x32_bf16(A0[ct], Bf, sc0[j], 0, 0, 0);
      sc1[j] = __builtin_amdgcn_mfma_f32_16x16x32_bf16(A1[ct], Bf, sc1[j], 0, 0, 0);
    }
  }

  // scale by inv_norm[row] * inv_norm[col]
  float iv0[4], iv1[4];
#pragma unroll
  for (int r = 0; r < 4; ++r) {
    int r0 = s0 * 16 + quad * 4 + r;
    int r1 = s1 * 16 + quad * 4 + r;
    iv0[r] = (r0 < 196) ? invn[b * 196 + r0] : 0.f;
    iv1[r] = (r1 < 196) ? invn[b * 196 + r1] : 0.f;
  }
#pragma unroll
  for (int j = 0; j < 13; ++j) {
    int m = j * 16 + l15;
    float ivB = (m < 196) ? invn[b * 196 + m] : 0.f;
#pragma unroll
    for (int r = 0; r < 4; ++r) {
      sc0[j][r] *= iv0[r] * ivB;
      sc1[j][r] *= iv1[r] * ivB;
    }
  }

  proc_strip(s0, sc0, AT, quad, l15);
  proc_strip(s1, sc1, AT, quad, l15);
}

// ---------------- Kernel: weighted GEMM + guide epilogue (v2+stats) --------
// [PROVEN round 2/5: ~103 µs.]
__global__ __launch_bounds__(256, 4) void k_weighted2(const float* __restrict__ sam,
                                                      const unsigned short* __restrict__ attnT,
                                                      const float* __restrict__ simw,
                                                      float* __restrict__ out,
                                                      float* __restrict__ stats) {
  const int b = blockIdx.x, q = blockIdx.y;
  const int tid = threadIdx.x, lane = tid & 63, wv = tid >> 6;
  const int quad = lane >> 4, l15 = lane & 15;
  const float* __restrict__ S = sam + (size_t)b * 50176;
  const unsigned short* __restrict__ AT = attnT + (size_t)b * (208 * 224);
  float* __restrict__ O = out + (size_t)b * 50176;
  const int cbase = q * 64 + wv * 16;

  __shared__ float tile[4][8 * 196];  // 25088 B, per-wave epilogue staging

  f32x4 acc[13];
  const f32x4 z4 = {0.f, 0.f, 0.f, 0.f};
#pragma unroll
  for (int mb = 0; mb < 13; ++mb) acc[mb] = z4;

  // A row for this lane: c = cbase + l15; k slice: kt*32 + quad*8 .. +7
  const float* __restrict__ Sa = S + (size_t)(cbase + l15) * 196;
  const unsigned short* __restrict__ Bp = AT + l15 * 224 + quad * 8;

#pragma unroll
  for (int kt = 0; kt < 7; ++kt) {
    s16x8 A;
    if (kt < 6) {
      const float* p = Sa + kt * 32 + quad * 8;
      A = pack8(*(const f32x4*)p, *(const f32x4*)(p + 4));
    } else {
      f32x4 lo = z4;
      if (quad == 0) lo = *(const f32x4*)(Sa + 192);
      A = pack8(lo, z4);
    }
    const unsigned short* Bk = Bp + kt * 32;
#pragma unroll
    for (int mb = 0; mb < 13; ++mb) {
      s16x8 Bf = *(const s16x8*)(Bk + mb * 16 * 224);
      acc[mb] = __builtin_amdgcn_mfma_f32_16x16x32_bf16(A, Bf, acc[mb], 0, 0, 0);
    }
  }

  // ---- epilogue: out[c][m] = (S[c][m] + acc) * simw[m] * 0.5 ----
  float wj0 = simw[b * 196 + lane] * 0.5f;
  float wj1 = simw[b * 196 + 64 + lane] * 0.5f;
  float wj2 = simw[b * 196 + 128 + lane] * 0.5f;
  float wj3 = 0.f;
  if (lane < 4) wj3 = simw[b * 196 + 192 + lane] * 0.5f;

  float st0 = 0.f, st1 = 0.f, st2 = 0.f, st3 = 0.f;
  float sq0 = 0.f, sq1 = 0.f, sq2 = 0.f, sq3 = 0.f;

  float* tl = &tile[wv][0];
  for (int half = 0; half < 2; ++half) {
    if ((quad >> 1) == half) {
      const int qq = quad & 1;
#pragma unroll
      for (int mb = 0; mb < 13; ++mb) {
        const int m = mb * 16 + l15;
        if (m < 196) {
#pragma unroll
          for (int r = 0; r < 4; ++r) tl[(qq * 4 + r) * 196 + m] = acc[mb][r];
        }
      }
    }
    __syncthreads();
    const int rowg0 = cbase + half * 8;
#pragma unroll
    for (int rr = 0; rr < 8; ++rr) {
      const float* trow = tl + rr * 196;
      const float* Sr = S + (size_t)(rowg0 + rr) * 196;
      float* Or = O + (size_t)(rowg0 + rr) * 196;
      float v0 = (Sr[lane] + trow[lane]) * wj0;
      float v1 = (Sr[lane + 64] + trow[lane + 64]) * wj1;
      float v2 = (Sr[lane + 128] + trow[lane + 128]) * wj2;
      Or[lane] = v0;
      Or[lane + 64] = v1;
      Or[lane + 128] = v2;
      st0 += v0; sq0 = fmaf(v0, v0, sq0);
      st1 += v1; sq1 = fmaf(v1, v1, sq1);
      st2 += v2; sq2 = fmaf(v2, v2, sq2);
      if (lane < 4) {
        float v3 = (Sr[lane + 192] + trow[lane + 192]) * wj3;
        Or[lane + 192] = v3;
        st3 += v3; sq3 = fmaf(v3, v3, sq3);
      }
    }
    __syncthreads();
  }

  // ---- channel-stat partials: per-wave regs -> LDS -> global (non-atomic)
  tl[lane] = st0; tl[lane + 64] = st1; tl[lane + 128] = st2;
  if (lane < 4) tl[lane + 192] = st3;
  tl[784 + lane] = sq0; tl[784 + lane + 64] = sq1; tl[784 + lane + 128] = sq2;
  if (lane < 4) tl[784 + lane + 192] = sq3;
  __syncthreads();
  if (tid < 196) {
    float s = tile[0][tid] + tile[1][tid] + tile[2][tid] + tile[3][tid];
    float qsum = tile[0][784 + tid] + tile[1][784 + tid] + tile[2][784 + tid] + tile[3][784 + tid];
    stats[((size_t)(b * 4 + q) * 2 + 0) * 196 + tid] = s;
    stats[((size_t)(b * 4 + q) * 2 + 1) * 196 + tid] = qsum;
  }
}

// ---------------- Kernel: hierarchical norm v2 -----------------------------
// [PROVEN round 2/5.]
__global__ __launch_bounds__(256) void k_norm2(float* __restrict__ x,
                                               const float* __restrict__ stats) {
  const int b = blockIdx.x, q = blockIdx.y, tid = threadIdx.x;
  float* __restrict__ X = x + (size_t)b * 50176 + (size_t)q * 128 * 196;
  __shared__ float s_mu[196], s_rs[196];
  __shared__ float s_rm[32], s_rc[32];
  __shared__ float T[32][197];

  if (tid < 196) {
    const float* st = stats + (size_t)b * 8 * 196;
    float s = st[tid] + st[2 * 196 + tid] + st[4 * 196 + tid] + st[6 * 196 + tid];
    float sq = st[196 + tid] + st[3 * 196 + tid] + st[5 * 196 + tid] + st[7 * 196 + tid];
    float mu = s * (1.0f / 256.0f);
    float var = sq * (1.0f / 256.0f) - mu * mu;
    s_mu[tid] = mu;
    s_rs[tid] = rsqrtf(fmaxf(var, 0.f) + 1e-5f);
  }
  __syncthreads();

  for (int rg = 0; rg < 4; ++rg) {
    float* Xg = X + rg * 32 * 196;
    for (int i = tid; i < 32 * 196; i += 256) T[i / 196][i % 196] = Xg[i];
    __syncthreads();
    const int r = tid >> 3, p = tid & 7;
    float ys = 0.f, yq = 0.f;
    for (int m = p; m < 196; m += 8) {
      float y = (T[r][m] - s_mu[m]) * s_rs[m];
      ys += y;
      yq = fmaf(y, y, yq);
    }
    ys += __shfl_xor(ys, 1, 64); yq += __shfl_xor(yq, 1, 64);
    ys += __shfl_xor(ys, 2, 64); yq += __shfl_xor(yq, 2, 64);
    ys += __shfl_xor(ys, 4, 64); yq += __shfl_xor(yq, 4, 64);
    if (p == 0) {
      float rm = ys * (1.0f / 196.0f);
      float var = (yq - 196.0f * rm * rm) * (1.0f / 195.0f);
      float sd = sqrtf(fmaxf(var, 0.f));
      s_rm[r] = rm;
      s_rc[r] = 1.0f / (sd + 1e-6f);
    }
    __syncthreads();
    for (int i = tid; i < 32 * 196; i += 256) {
      int rr = i / 196, m = i % 196;
      float y = (T[rr][m] - s_mu[m]) * s_rs[m];
      Xg[i] = (y - s_rm[rr]) * s_rc[rr];
    }
    __syncthreads();
  }
}

// ---------------- Fallback fp32 fused attention ----------------------------
__global__ __launch_bounds__(256) void k_attn(const float* __restrict__ sam,
                                              const float* __restrict__ simw,
                                              float* __restrict__ out) {
  const int b = blockIdx.x;
  const int tid = threadIdx.x, lane = tid & 63, wv = tid >> 6;
  const float* __restrict__ S = sam + (size_t)b * (256 * 196);
  float* __restrict__ O = out + (size_t)b * (256 * 196);
  const float* __restrict__ SW = simw + b * 196;

  __shared__ float s_inv[196];
  __shared__ float s_max[196];
  __shared__ float s_rsum[196];
  __shared__ float bufS[28 * 197];
  __shared__ float bufT[256 * 29];

  for (int l = tid; l < 196; l += 256) {
    float ss = 0.f;
    for (int c = 0; c < 256; ++c) {
      float v = S[c * 196 + l];
      ss = fmaf(v, v, ss);
    }
    s_inv[l] = 1.0f / fmaxf(sqrtf(ss), 1e-12f);
  }

  for (int r0 = 0; r0 < 196; r0 += 28) {
    float acc[7][4];
#pragma unroll
    for (int i = 0; i < 7; ++i)
#pragma unroll
      for (int j = 0; j < 4; ++j) acc[i][j] = 0.f;
    const int lr = r0 + wv * 7;
    for (int ct = 0; ct < 8; ++ct) {
      __syncthreads();
      for (int i = tid; i < 32 * 196; i += 256)
        bufT[(i / 196) * 197 + (i % 196)] = S[ct * 32 * 196 + i];
      __syncthreads();
#pragma unroll 2
      for (int c = 0; c < 32; ++c) {
        const float* row = bufT + c * 197;
        float a[7];
#pragma unroll
        for (int i = 0; i < 7; ++i) a[i] = row[lr + i];
        float b0 = row[lane], b1 = row[lane + 64], b2 = row[lane + 128];
        float b3 = row[lane + 192];
#pragma unroll
        for (int i = 0; i < 7; ++i) {
          acc[i][0] = fmaf(a[i], b0, acc[i][0]);
          acc[i][1] = fmaf(a[i], b1, acc[i][1]);
          acc[i][2] = fmaf(a[i], b2, acc[i][2]);
          acc[i][3] = fmaf(a[i], b3, acc[i][3]);
        }
      }
    }
#pragma unroll
    for (int j = 0; j < 4; ++j) {
      int m = lane + 64 * j;
      if (m < 196) {
        float im = s_inv[m] * 0.0625f;
#pragma unroll
        for (int i = 0; i < 7; ++i)
          bufS[(wv * 7 + i) * 197 + m] = acc[i][j] * s_inv[lr + i] * im;
      }
    }
    __syncthreads();
#pragma unroll
    for (int i = 0; i < 7; ++i) {
      const int rl = wv * 7 + i;
      const float* sr = bufS + rl * 197;
      float v0 = sr[lane], v1 = sr[lane + 64], v2 = sr[lane + 128];
      bool g = (lane + 192) < 196;
      float v3 = g ? sr[lane + 192] : -1e30f;
      float mxv = fmaxf(fmaxf(v0, v1), fmaxf(v2, v3));
#pragma unroll
      for (int o = 32; o > 0; o >>= 1) mxv = fmaxf(mxv, __shfl_xor(mxv, o, 64));
      float sm = __expf(v0 - mxv) + __expf(v1 - mxv) + __expf(v2 - mxv) +
                 (g ? __expf(v3 - mxv) : 0.f);
      sm = wsum(sm);
      if (lane == 0) { s_max[r0 + rl] = mxv; s_rsum[r0 + rl] = 1.0f / sm; }
    }
  }
  __syncthreads();

  const int cg = tid >> 2, tq = tid & 3;
  for (int m0 = 0; m0 < 196; m0 += 28) {
    float acc[7][4];
#pragma unroll
    for (int i = 0; i < 7; ++i)
#pragma unroll
      for (int j = 0; j < 4; ++j) acc[i][j] = 0.f;
    const int mg = m0 + wv * 7;
    for (int ct = 0; ct < 8; ++ct) {
      __syncthreads();
      for (int i = tid; i < 32 * 196; i += 256)
        bufT[(i / 196) * 197 + (i % 196)] = S[ct * 32 * 196 + i];
      __syncthreads();
#pragma unroll 2
      for (int c = 0; c < 32; ++c) {
        const float* row = bufT + c * 197;
        float a[7];
#pragma unroll
        for (int i = 0; i < 7; ++i) a[i] = row[mg + i];
        float b0 = row[lane], b1 = row[lane + 64], b2 = row[lane + 128];
        float b3 = row[lane + 192];
#pragma unroll
        for (int i = 0; i < 7; ++i) {
          acc[i][0] = fmaf(a[i], b0, acc[i][0]);
          acc[i][1] = fmaf(a[i], b1, acc[i][1]);
          acc[i][2] = fmaf(a[i], b2, acc[i][2]);
          acc[i][3] = fmaf(a[i], b3, acc[i][3]);
        }
      }
    }
    __syncthreads();
#pragma unroll
    for (int j = 0; j < 4; ++j) {
      int l = lane + 64 * j;
      if (l < 196) {
        float il = s_inv[l] * 0.0625f;
        float mxl = s_max[l], rsl = s_rsum[l];
#pragma unroll
        for (int i = 0; i < 7; ++i) {
          float sc = acc[i][j] * s_inv[mg + i] * il;
          bufS[(wv * 7 + i) * 197 + l] = __expf(sc - mxl) * rsl;
        }
      }
    }
    __syncthreads();
    float w[4][7];
#pragma unroll
    for (int ii = 0; ii < 4; ++ii)
#pragma unroll
      for (int i = 0; i < 7; ++i) w[ii][i] = 0.f;
    for (int lt = 0; lt < 7; ++lt) {
      __syncthreads();
      for (int i = tid; i < 256 * 28; i += 256) {
        int c = i / 28, j = i - c * 28;
        bufT[c * 29 + j] = S[c * 196 + lt * 28 + j];
      }
      __syncthreads();
#pragma unroll 4
      for (int j = 0; j < 28; ++j) {
        float a0 = bufT[(cg * 4 + 0) * 29 + j];
        float a1 = bufT[(cg * 4 + 1) * 29 + j];
        float a2 = bufT[(cg * 4 + 2) * 29 + j];
        float a3 = bufT[(cg * 4 + 3) * 29 + j];
#pragma unroll
        for (int i = 0; i < 7; ++i) {
          float bv = bufS[(tq * 7 + i) * 197 + lt * 28 + j];
          w[0][i] = fmaf(a0, bv, w[0][i]);
          w[1][i] = fmaf(a1, bv, w[1][i]);
          w[2][i] = fmaf(a2, bv, w[2][i]);
          w[3][i] = fmaf(a3, bv, w[3][i]);
        }
      }
    }
#pragma unroll
    for (int i = 0; i < 7; ++i) {
      const int m = m0 + tq * 7 + i;
      float sw = SW[m] * 0.5f;
#pragma unroll
      for (int ii = 0; ii < 4; ++ii) {
        const int c = cg * 4 + ii;
        O[c * 196 + m] = (S[c * 196 + m] + w[ii][i]) * sw;
      }
    }
  }
}

// ---------------- Kernel: hierarchical norm (fallback, in-place) -----------
__global__ __launch_bounds__(256) void k_norm(float* __restrict__ x) {
  const int b = blockIdx.x, tid = threadIdx.x;
  float* __restrict__ X = x + (size_t)b * (256 * 196);
  __shared__ float s_mu[196], s_rs[196];
  __shared__ float s_rm[256], s_rc[256];
  __shared__ float tile[256 * 29];

  if (tid < 196) {
    float s = 0.f, q = 0.f;
    for (int c = 0; c < 256; ++c) {
      float v = X[c * 196 + tid];
      s += v;
      q = fmaf(v, v, q);
    }
    float mu = s * (1.0f / 256.0f);
    float var = q * (1.0f / 256.0f) - mu * mu;
    s_mu[tid] = mu;
    s_rs[tid] = rsqrtf(fmaxf(var, 0.f) + 1e-5f);
  }
  __syncthreads();

  float rs = 0.f, rq = 0.f;
  for (int m0 = 0; m0 < 196; m0 += 28) {
    __syncthreads();
    for (int i = tid; i < 256 * 28; i += 256) {
      int c = i / 28, j = i - c * 28;
      tile[c * 29 + j] = X[c * 196 + m0 + j];
    }
    __syncthreads();
#pragma unroll
    for (int j = 0; j < 28; ++j) {
      float y = (tile[tid * 29 + j] - s_mu[m0 + j]) * s_rs[m0 + j];
      rs += y;
      rq = fmaf(y, y, rq);
    }
  }
  float rm = rs * (1.0f / 196.0f);
  float var = (rq - 196.0f * rm * rm) * (1.0f / 195.0f);
  float sd = sqrtf(fmaxf(var, 0.f));
  s_rm[tid] = rm;
  s_rc[tid] = 1.0f / (sd + 1e-6f);
  __syncthreads();

  for (int i = tid; i < 256 * 196; i += 256) {
    int c = i / 196, m = i - c * 196;
    float y = (X[i] - s_mu[m]) * s_rs[m];
    X[i] = (y - s_rm[c]) * s_rc[c];
  }
}

extern "C" void kernel_launch(void* const* d_in, const int* in_sizes, int n_in,
                              void* d_out, int out_size, void* d_ws, size_t ws_size,
                              hipStream_t stream) {
  const float* img = (const float*)d_in[0];
  const float* txt = (const float*)d_in[1];
  const float* sam = (const float*)d_in[2];
  const float* Wsim = (const float*)d_in[3];
  const float* bsim = (const float*)d_in[4];
  float* out = (float*)d_out;

  const int B = in_sizes[0] / 512;  // 512

  const size_t simw_bytes = (((size_t)B * 196 * 4) + 511) & ~(size_t)511;
  const size_t samnT_bytes = (size_t)B * 208 * 256 * 2;
  const size_t attnT_bytes = (size_t)B * 208 * 224 * 2;
  const size_t stats_bytes = (size_t)B * 4 * 2 * 196 * 4;
  const size_t invn_bytes = (((size_t)B * 196 * 4) + 511) & ~(size_t)511;
  const size_t need = simw_bytes + samnT_bytes + attnT_bytes + stats_bytes + invn_bytes;

  float* simw = (float*)d_ws;

  k_simw<<<B, 256, 0, stream>>>(img, txt, Wsim, bsim, simw);

  if (ws_size >= need) {
    unsigned short* samnT = (unsigned short*)((char*)d_ws + simw_bytes);
    unsigned short* attnT = (unsigned short*)((char*)d_ws + simw_bytes + samnT_bytes);
    float* stats = (float*)((char*)d_ws + simw_bytes + samnT_bytes + attnT_bytes);
    float* invn = (float*)((char*)d_ws + simw_bytes + samnT_bytes + attnT_bytes + stats_bytes);
    k_prep2<<<B, 256, 0, stream>>>(sam, samnT, attnT, invn);
    k_scores3<<<B * 7, 64, 0, stream>>>(samnT, invn, attnT);
    k_weighted2<<<dim3(B, 4), 256, 0, stream>>>(sam, attnT, simw, out, stats);
    k_norm2<<<dim3(B, 2), 256, 0, stream>>>(out, stats);
  } else {
    k_attn<<<B, 256, 0, stream>>>(sam, simw, out);
    k_norm<<<B, 256, 0, stream>>>(out);
  }
}